// Round 6
// baseline (553.512 us; speedup 1.0000x reference)
//
#include <hip/hip_runtime.h>
#include <hip/hip_bf16.h>
#include <stdint.h>

// Problem constants
#define B_N 1024
#define S_N 65536
#define D_N 512
#define SCALE 8.0f
#define KSPLIT 32
#define KCHUNK (S_N / KSPLIT)   // 2048

typedef __attribute__((ext_vector_type(8))) short bf16x8;   // 8 bf16 in 4 VGPRs
typedef __attribute__((ext_vector_type(4))) float f32x4;
typedef __attribute__((ext_vector_type(4))) unsigned int u32x4;  // clang vec for nontemporal builtins

// ---- workspace layout (bytes) ----
// Opart (64 MiB, KSPLIT=32) overlays Mbf: Mbf is dead once k_qk completes.
#define OFF_MBF   ((size_t)0)                                  // M bf16 (s,d)   64 MiB (reused as Opart)
#define OFF_MT    (OFF_MBF + (size_t)S_N * D_N * 2)            // M^T bf16 (d,s) 64 MiB
#define OFF_XBF   (OFF_MT  + (size_t)D_N * S_N * 2)            // X bf16         1 MiB
#define OFF_P     (OFF_XBF + (size_t)B_N * D_N * 2)            // P=exp bf16     128 MiB
#define OFF_XNSQ  (OFF_P   + (size_t)B_N * S_N * 2)            // rsqrt(||x||^2) 4 KiB
#define OFF_MNSQ  (OFF_XNSQ + (size_t)B_N * 4)                 // rsqrt(||m||^2) 256 KiB
#define OFF_LSUM  (OFF_MNSQ + (size_t)S_N * 4)                 // softmax denom  4 KiB
#define OFF_OPART OFF_MBF

__device__ __forceinline__ unsigned short f2bf(float f) {
  unsigned u = __builtin_bit_cast(unsigned, f);
  u += 0x7fffu + ((u >> 16) & 1u);          // RNE
  return (unsigned short)(u >> 16);
}

__device__ __forceinline__ void stage16(const unsigned short* g, unsigned short* l) {
  // async global->LDS, 16B/lane; LDS dest is wave-uniform base + lane*16
  __builtin_amdgcn_global_load_lds(
      (const __attribute__((address_space(1))) void*)g,
      (__attribute__((address_space(3))) void*)l, 16, 0, 0);
}

// ---------------- prep X: bf16 convert + rsqrt(||x||^2) ----------------
__global__ void k_prep_x(const float* __restrict__ X, unsigned short* __restrict__ Xbf,
                         float* __restrict__ rsx) {
  const int row = blockIdx.x;
  const int t = threadIdx.x;  // 0..127
  float4 v = ((const float4*)(X + (size_t)row * D_N))[t];
  float ss = v.x*v.x + v.y*v.y + v.z*v.z + v.w*v.w;
  ushort4 o; o.x = f2bf(v.x); o.y = f2bf(v.y); o.z = f2bf(v.z); o.w = f2bf(v.w);
  ((ushort4*)(Xbf + (size_t)row * D_N))[t] = o;
  #pragma unroll
  for (int m = 1; m < 64; m <<= 1) ss += __shfl_xor(ss, m);
  __shared__ float partial[2];
  if ((t & 63) == 0) partial[t >> 6] = ss;
  __syncthreads();
  if (t == 0) rsx[row] = rsqrtf(partial[0] + partial[1]);
}

// ------- prep M: bf16 convert, LDS-transpose to Mt, rsqrt(||m||^2) -------
// Mt stores nontemporal: Mt isn't read until k_pv (after k_qk); keep LLC for Mbf/P.
__global__ void k_prep_m(const float* __restrict__ M, unsigned short* __restrict__ Mbf,
                         unsigned short* __restrict__ Mt, float* __restrict__ rsm) {
  __shared__ float ts[64 * 65];
  const int t = threadIdx.x;                // 256
  const int s0 = blockIdx.x * 64;
  const int r = t >> 2, cq = t & 3;
  const int c = t >> 2, sq = t & 3;
  float ss = 0.f;
  for (int ct = 0; ct < 8; ++ct) {
    float f[16];
    const float4* src = (const float4*)(M + (size_t)(s0 + r) * D_N + ct * 64 + cq * 16);
    #pragma unroll
    for (int k = 0; k < 4; ++k) {
      float4 v = src[k];
      f[4*k+0] = v.x; f[4*k+1] = v.y; f[4*k+2] = v.z; f[4*k+3] = v.w;
    }
    union { unsigned short u[16]; uint4 v4[2]; } pk;
    #pragma unroll
    for (int j = 0; j < 16; ++j) {
      ss += f[j] * f[j];
      pk.u[j] = f2bf(f[j]);
      ts[r * 65 + cq * 16 + j] = f[j];
    }
    uint4* dst = (uint4*)(Mbf + (size_t)(s0 + r) * D_N + ct * 64 + cq * 16);
    dst[0] = pk.v4[0]; dst[1] = pk.v4[1];
    __syncthreads();
    union { unsigned short u[16]; u32x4 v4[2]; } pt;
    #pragma unroll
    for (int j = 0; j < 16; ++j) pt.u[j] = f2bf(ts[(sq * 16 + j) * 65 + c]);
    u32x4* dt = (u32x4*)(Mt + (size_t)(ct * 64 + c) * S_N + s0 + sq * 16);
    __builtin_nontemporal_store(pt.v4[0], dt + 0);
    __builtin_nontemporal_store(pt.v4[1], dt + 1);
    __syncthreads();
  }
  ss += __shfl_xor(ss, 1);
  ss += __shfl_xor(ss, 2);
  if (cq == 0) rsm[s0 + r] = rsqrtf(ss);
}

// ---------------- QK gemm_bt + exp epilogue (LDS-coalesced P store) ----------------
// K-loop: round-2 verified structure (global_load_lds + __syncthreads, source-side
// XOR swizzle, SQ_LDS_BANK_CONFLICT=0). Epilogue: fragments -> LDS (64 rows x
// stride-136 shorts, two half-passes reusing the staging buffer) -> 64B-contiguous
// dwordx4 stores per thread so each P line is written whole (no L2-merge reliance).
#define PS_STRIDE 136
__global__ __launch_bounds__(256, 4) void k_qk(
    const unsigned short* __restrict__ Xbf, const unsigned short* __restrict__ Mbf,
    const float* __restrict__ rsx, const float* __restrict__ rsm,
    unsigned short* __restrict__ P, float* __restrict__ lsum) {
  __shared__ __align__(16) unsigned char smem[32768];
  unsigned short* As = (unsigned short*)smem;            // 16 KiB staging A
  unsigned short* Bs = (unsigned short*)(smem + 16384);  // 16 KiB staging B
  unsigned short* Ps = (unsigned short*)smem;            // epilogue stage (17408 B), reuses staging
  const int t = threadIdx.x;
  const int w = t >> 6, lane = t & 63, quad = lane >> 4, l15 = lane & 15;
  const int wr = w >> 1, wc = w & 1;
  const int x7 = l15 & 7;
  // XCD swizzle: xcd = flat&7; each XCD owns 64 consecutive bn values.
  const int flat = blockIdx.x;
  const int xcd = flat & 7, sl = flat >> 3;
  const int bn = xcd * 64 + (sl >> 3);
  const int bm = sl & 7;

  f32x4 acc[4][4];
  #pragma unroll
  for (int i = 0; i < 4; ++i)
    #pragma unroll
    for (int j = 0; j < 4; ++j) acc[i][j] = (f32x4){0.f, 0.f, 0.f, 0.f};

  const int srow = t >> 3;
  const int schunk = (t & 7) ^ (srow & 7);      // inverse swizzle at load time
  const unsigned short* gA = Xbf + (size_t)(bm * 128 + srow) * D_N + schunk * 8;
  const unsigned short* gB = Mbf + (size_t)(bn * 128 + srow) * D_N + schunk * 8;
  unsigned short* lA = As + w * 512;
  unsigned short* lB = Bs + w * 512;

  for (int k0 = 0; k0 < D_N; k0 += 64) {
    #pragma unroll
    for (int i = 0; i < 4; ++i) {
      stage16(gA + (size_t)(i * 32) * D_N + k0, lA + i * 2048);
      stage16(gB + (size_t)(i * 32) * D_N + k0, lB + i * 2048);
    }
    __syncthreads();
    #pragma unroll
    for (int kk = 0; kk < 64; kk += 32) {
      const int cq = (kk >> 3) + quad;          // logical chunk
      bf16x8 af[4], bfr[4];
      #pragma unroll
      for (int i = 0; i < 4; ++i)
        af[i] = *(const bf16x8*)&As[(wr * 64 + i * 16 + l15) * 64 + (cq ^ x7) * 8];
      #pragma unroll
      for (int j = 0; j < 4; ++j)
        bfr[j] = *(const bf16x8*)&Bs[(wc * 64 + j * 16 + l15) * 64 + (cq ^ x7) * 8];
      #pragma unroll
      for (int i = 0; i < 4; ++i)
        #pragma unroll
        for (int j = 0; j < 4; ++j)
          acc[i][j] = __builtin_amdgcn_mfma_f32_16x16x32_bf16(af[i], bfr[j], acc[i][j], 0, 0, 0);
    }
    __syncthreads();
  }

  float rm_[4];
  #pragma unroll
  for (int j = 0; j < 4; ++j) rm_[j] = rsm[bn * 128 + wc * 64 + j * 16 + l15];

  #pragma unroll
  for (int half = 0; half < 2; ++half) {
    if (wr == half) {          // wave-uniform branch: waves wr==half own rows [half*64, half*64+64)
      #pragma unroll
      for (int i = 0; i < 4; ++i) {
        #pragma unroll
        for (int r = 0; r < 4; ++r) {
          const int lrow = i * 16 + quad * 4 + r;        // 0..63 within half
          const int b = bm * 128 + half * 64 + lrow;
          const float srx = SCALE * rsx[b];
          float rs = 0.f;
          #pragma unroll
          for (int j = 0; j < 4; ++j) {
            float p = __expf(acc[i][j][r] * srx * rm_[j]);
            rs += p;
            Ps[lrow * PS_STRIDE + wc * 64 + j * 16 + l15] = f2bf(p);
          }
          rs += __shfl_xor(rs, 1);
          rs += __shfl_xor(rs, 2);
          rs += __shfl_xor(rs, 4);
          rs += __shfl_xor(rs, 8);
          if (l15 == 0) unsafeAtomicAdd(&lsum[b], rs);
        }
      }
    }
    __syncthreads();
    // cooperative coalesced store of rows [half*64, half*64+64): 64B contiguous/thread
    {
      const int row = t >> 2, c4 = t & 3;
      const int gb = bm * 128 + half * 64 + row;
      const unsigned short* src = &Ps[row * PS_STRIDE + c4 * 32];
      uint4 v[4];
      #pragma unroll
      for (int k = 0; k < 4; ++k) v[k] = *(const uint4*)(src + k * 8);
      uint4* dst = (uint4*)&P[(size_t)gb * S_N + bn * 128 + c4 * 32];
      #pragma unroll
      for (int k = 0; k < 4; ++k) dst[k] = v[k];
    }
    __syncthreads();
  }
}

// ---------------- PV gemm_bt (K-split 32) ----------------
// Opart[ks][b][d] = sum_{s in chunk} P[b][s] * Mt[d][s]
__global__ __launch_bounds__(256, 4) void k_pv(
    const unsigned short* __restrict__ P, const unsigned short* __restrict__ Mt,
    float* __restrict__ Opart) {
  __shared__ unsigned short As[128 * 64];
  __shared__ unsigned short Bs[128 * 64];
  const int t = threadIdx.x;
  const int w = t >> 6, lane = t & 63, quad = lane >> 4, l15 = lane & 15;
  const int wr = w >> 1, wc = w & 1;
  const int x7 = l15 & 7;
  const int flat = blockIdx.x;
  const int xcd = flat & 7, sl = flat >> 3;     // sl 0..127
  const int ks = xcd * 4 + (sl >> 5);           // 4 ks per XCD
  const int rem = sl & 31;
  const int bn = rem >> 3, bm = rem & 7;

  f32x4 acc[4][4];
  #pragma unroll
  for (int i = 0; i < 4; ++i)
    #pragma unroll
    for (int j = 0; j < 4; ++j) acc[i][j] = (f32x4){0.f, 0.f, 0.f, 0.f};

  const int srow = t >> 3;
  const int schunk = (t & 7) ^ (srow & 7);
  const unsigned short* gA = P  + (size_t)(bm * 128 + srow) * S_N + (size_t)ks * KCHUNK + schunk * 8;
  const unsigned short* gB = Mt + (size_t)(bn * 128 + srow) * S_N + (size_t)ks * KCHUNK + schunk * 8;
  unsigned short* lA = As + w * 512;
  unsigned short* lB = Bs + w * 512;

  for (int k0 = 0; k0 < KCHUNK; k0 += 64) {
    #pragma unroll
    for (int i = 0; i < 4; ++i) {
      stage16(gA + (size_t)(i * 32) * S_N + k0, lA + i * 2048);
      stage16(gB + (size_t)(i * 32) * S_N + k0, lB + i * 2048);
    }
    __syncthreads();
    #pragma unroll
    for (int kk = 0; kk < 64; kk += 32) {
      const int cq = (kk >> 3) + quad;
      bf16x8 af[4], bfr[4];
      #pragma unroll
      for (int i = 0; i < 4; ++i)
        af[i] = *(const bf16x8*)&As[(wr * 64 + i * 16 + l15) * 64 + (cq ^ x7) * 8];
      #pragma unroll
      for (int j = 0; j < 4; ++j)
        bfr[j] = *(const bf16x8*)&Bs[(wc * 64 + j * 16 + l15) * 64 + (cq ^ x7) * 8];
      #pragma unroll
      for (int i = 0; i < 4; ++i)
        #pragma unroll
        for (int j = 0; j < 4; ++j)
          acc[i][j] = __builtin_amdgcn_mfma_f32_16x16x32_bf16(af[i], bfr[j], acc[i][j], 0, 0, 0);
    }
    __syncthreads();
  }

  float* Od = Opart + (size_t)ks * (B_N * D_N);
  #pragma unroll
  for (int i = 0; i < 4; ++i)
    #pragma unroll
    for (int r = 0; r < 4; ++r) {
      const int b = bm * 128 + wr * 64 + i * 16 + quad * 4 + r;
      #pragma unroll
      for (int j = 0; j < 4; ++j) {
        const int d = bn * 128 + wc * 64 + j * 16 + l15;
        Od[(size_t)b * D_N + d] = acc[i][j][r];
      }
    }
}

// ---------------- combine: out = (sum_ks Opart) / lsum ----------------
__global__ void k_combine(const float* __restrict__ Opart, const float* __restrict__ lsum,
                          float* __restrict__ out) {
  const int idx = blockIdx.x * 256 + threadIdx.x;  // float4 index, 131072 total
  const int b = idx >> 7;
  float4 s = {0.f, 0.f, 0.f, 0.f};
  #pragma unroll
  for (int ks = 0; ks < KSPLIT; ++ks) {
    float4 v = ((const float4*)Opart)[(size_t)ks * (B_N * D_N / 4) + idx];
    s.x += v.x; s.y += v.y; s.z += v.z; s.w += v.w;
  }
  const float inv = 1.0f / lsum[b];
  s.x *= inv; s.y *= inv; s.z *= inv; s.w *= inv;
  ((float4*)out)[idx] = s;
}

extern "C" void kernel_launch(void* const* d_in, const int* in_sizes, int n_in,
                              void* d_out, int out_size, void* d_ws, size_t ws_size,
                              hipStream_t stream) {
  const float* X = (const float*)d_in[0];
  const float* M = (const float*)d_in[1];
  char* ws = (char*)d_ws;
  unsigned short* Mbf  = (unsigned short*)(ws + OFF_MBF);
  unsigned short* Mt   = (unsigned short*)(ws + OFF_MT);
  unsigned short* Xbf  = (unsigned short*)(ws + OFF_XBF);
  unsigned short* P    = (unsigned short*)(ws + OFF_P);
  float* rsx = (float*)(ws + OFF_XNSQ);
  float* rsm = (float*)(ws + OFF_MNSQ);
  float* lsum = (float*)(ws + OFF_LSUM);
  float* Opart = (float*)(ws + OFF_OPART);    // overlays Mbf (dead after k_qk)

  (void)hipMemsetAsync(lsum, 0, B_N * sizeof(float), stream);
  k_prep_x<<<dim3(B_N), 128, 0, stream>>>(X, Xbf, rsx);
  k_prep_m<<<dim3(S_N / 64), 256, 0, stream>>>(M, Mbf, Mt, rsm);
  k_qk<<<dim3(8 * (S_N / 128)), 256, 0, stream>>>(Xbf, Mbf, rsx, rsm, P, lsum);
  k_pv<<<dim3((D_N / 128) * (B_N / 128) * KSPLIT), 256, 0, stream>>>(P, Mt, Opart);
  k_combine<<<dim3(B_N * D_N / 4 / 256), 256, 0, stream>>>(Opart, lsum, (float*)d_out);
}

// Round 7
// 515.197 us; speedup vs baseline: 1.0744x; 1.0744x over previous
//
#include <hip/hip_runtime.h>
#include <hip/hip_bf16.h>
#include <stdint.h>

// Problem constants
#define B_N 1024
#define S_N 65536
#define D_N 512
#define SCALE 8.0f
#define KSPLIT 32
#define KCHUNK (S_N / KSPLIT)   // 2048

typedef __attribute__((ext_vector_type(8))) short bf16x8;   // 8 bf16 in 4 VGPRs
typedef __attribute__((ext_vector_type(4))) float f32x4;
typedef __attribute__((ext_vector_type(4))) unsigned int u32x4;  // clang vec for nontemporal builtins

// ---- workspace layout (bytes) ----
// Opart (64 MiB, KSPLIT=32) overlays Mbf: Mbf is dead once k_qk completes.
#define OFF_MBF   ((size_t)0)                                  // M bf16 (s,d)   64 MiB (reused as Opart)
#define OFF_MT    (OFF_MBF + (size_t)S_N * D_N * 2)            // M^T bf16 (d,s) 64 MiB
#define OFF_XBF   (OFF_MT  + (size_t)D_N * S_N * 2)            // X bf16         1 MiB
#define OFF_P     (OFF_XBF + (size_t)B_N * D_N * 2)            // P=exp bf16     128 MiB
#define OFF_XNSQ  (OFF_P   + (size_t)B_N * S_N * 2)            // rsqrt(||x||^2) 4 KiB
#define OFF_MNSQ  (OFF_XNSQ + (size_t)B_N * 4)                 // rsqrt(||m||^2) 256 KiB
#define OFF_LSUM  (OFF_MNSQ + (size_t)S_N * 4)                 // softmax denom  4 KiB
#define OFF_OPART OFF_MBF

__device__ __forceinline__ unsigned short f2bf(float f) {
  unsigned u = __builtin_bit_cast(unsigned, f);
  u += 0x7fffu + ((u >> 16) & 1u);          // RNE
  return (unsigned short)(u >> 16);
}

__device__ __forceinline__ void stage16(const unsigned short* g, unsigned short* l) {
  // async global->LDS, 16B/lane; LDS dest is wave-uniform base + lane*16
  __builtin_amdgcn_global_load_lds(
      (const __attribute__((address_space(1))) void*)g,
      (__attribute__((address_space(3))) void*)l, 16, 0, 0);
}

// ---------------- prep X: bf16 convert + rsqrt(||x||^2) ----------------
__global__ void k_prep_x(const float* __restrict__ X, unsigned short* __restrict__ Xbf,
                         float* __restrict__ rsx) {
  const int row = blockIdx.x;
  const int t = threadIdx.x;  // 0..127
  float4 v = ((const float4*)(X + (size_t)row * D_N))[t];
  float ss = v.x*v.x + v.y*v.y + v.z*v.z + v.w*v.w;
  ushort4 o; o.x = f2bf(v.x); o.y = f2bf(v.y); o.z = f2bf(v.z); o.w = f2bf(v.w);
  ((ushort4*)(Xbf + (size_t)row * D_N))[t] = o;
  #pragma unroll
  for (int m = 1; m < 64; m <<= 1) ss += __shfl_xor(ss, m);
  __shared__ float partial[2];
  if ((t & 63) == 0) partial[t >> 6] = ss;
  __syncthreads();
  if (t == 0) rsx[row] = rsqrtf(partial[0] + partial[1]);
}

// ------- prep M: bf16 convert, LDS-transpose to Mt, rsqrt(||m||^2) -------
// Mt stores nontemporal: Mt isn't read until k_pv (after k_qk); keep LLC for Mbf/P.
__global__ void k_prep_m(const float* __restrict__ M, unsigned short* __restrict__ Mbf,
                         unsigned short* __restrict__ Mt, float* __restrict__ rsm) {
  __shared__ float ts[64 * 65];
  const int t = threadIdx.x;                // 256
  const int s0 = blockIdx.x * 64;
  const int r = t >> 2, cq = t & 3;
  const int c = t >> 2, sq = t & 3;
  float ss = 0.f;
  for (int ct = 0; ct < 8; ++ct) {
    float f[16];
    const float4* src = (const float4*)(M + (size_t)(s0 + r) * D_N + ct * 64 + cq * 16);
    #pragma unroll
    for (int k = 0; k < 4; ++k) {
      float4 v = src[k];
      f[4*k+0] = v.x; f[4*k+1] = v.y; f[4*k+2] = v.z; f[4*k+3] = v.w;
    }
    union { unsigned short u[16]; uint4 v4[2]; } pk;
    #pragma unroll
    for (int j = 0; j < 16; ++j) {
      ss += f[j] * f[j];
      pk.u[j] = f2bf(f[j]);
      ts[r * 65 + cq * 16 + j] = f[j];
    }
    uint4* dst = (uint4*)(Mbf + (size_t)(s0 + r) * D_N + ct * 64 + cq * 16);
    dst[0] = pk.v4[0]; dst[1] = pk.v4[1];
    __syncthreads();
    union { unsigned short u[16]; u32x4 v4[2]; } pt;
    #pragma unroll
    for (int j = 0; j < 16; ++j) pt.u[j] = f2bf(ts[(sq * 16 + j) * 65 + c]);
    u32x4* dt = (u32x4*)(Mt + (size_t)(ct * 64 + c) * S_N + s0 + sq * 16);
    __builtin_nontemporal_store(pt.v4[0], dt + 0);
    __builtin_nontemporal_store(pt.v4[1], dt + 1);
    __syncthreads();
  }
  ss += __shfl_xor(ss, 1);
  ss += __shfl_xor(ss, 2);
  if (cq == 0) rsm[s0 + r] = rsqrtf(ss);
}

// ---------------- QK gemm_bt, DOUBLE-BUFFERED, + exp epilogue ----------------
// Pipeline per iter: [issue loads -> buf[next]] [compute from buf[cur]] [barrier].
// The per-wave vmcnt(0) drain at the barrier lands a full compute-phase after
// issue -> load latency overlapped. One barrier per iteration. LDS 64 KiB ->
// 2 blocks/CU (ILP replaces TLP). Source-side XOR swizzle (conflict-free, R2-verified).
__global__ __launch_bounds__(256, 2) void k_qk(
    const unsigned short* __restrict__ Xbf, const unsigned short* __restrict__ Mbf,
    const float* __restrict__ rsx, const float* __restrict__ rsm,
    unsigned short* __restrict__ P, float* __restrict__ lsum) {
  __shared__ unsigned short As[2][128 * 64];
  __shared__ unsigned short Bs[2][128 * 64];
  const int t = threadIdx.x;
  const int w = t >> 6, lane = t & 63, quad = lane >> 4, l15 = lane & 15;
  const int wr = w >> 1, wc = w & 1;
  const int x7 = l15 & 7;
  // XCD swizzle: xcd = flat&7; each XCD owns 64 consecutive bn values.
  const int flat = blockIdx.x;
  const int xcd = flat & 7, sl = flat >> 3;
  const int bn = xcd * 64 + (sl >> 3);
  const int bm = sl & 7;

  f32x4 acc[4][4];
  #pragma unroll
  for (int i = 0; i < 4; ++i)
    #pragma unroll
    for (int j = 0; j < 4; ++j) acc[i][j] = (f32x4){0.f, 0.f, 0.f, 0.f};

  const int srow = t >> 3;
  const int schunk = (t & 7) ^ (srow & 7);      // inverse swizzle at load time
  const unsigned short* gA = Xbf + (size_t)(bm * 128 + srow) * D_N + schunk * 8;
  const unsigned short* gB = Mbf + (size_t)(bn * 128 + srow) * D_N + schunk * 8;
  const int lofs = w * 512;

  // preload tile 0 into buf 0
  #pragma unroll
  for (int i = 0; i < 4; ++i) {
    stage16(gA + (size_t)(i * 32) * D_N, As[0] + lofs + i * 2048);
    stage16(gB + (size_t)(i * 32) * D_N, Bs[0] + lofs + i * 2048);
  }

  #pragma unroll
  for (int it = 0; it < 8; ++it) {
    __syncthreads();                            // drains loads issued last iter
    if (it < 7) {
      const int k0 = (it + 1) * 64;
      unsigned short* nA = As[(it + 1) & 1] + lofs;
      unsigned short* nB = Bs[(it + 1) & 1] + lofs;
      #pragma unroll
      for (int i = 0; i < 4; ++i) {
        stage16(gA + (size_t)(i * 32) * D_N + k0, nA + i * 2048);
        stage16(gB + (size_t)(i * 32) * D_N + k0, nB + i * 2048);
      }
    }
    const unsigned short* Ab = As[it & 1];
    const unsigned short* Bb = Bs[it & 1];
    #pragma unroll
    for (int kk = 0; kk < 64; kk += 32) {
      const int cq = (kk >> 3) + quad;          // logical chunk
      bf16x8 af[4], bfr[4];
      #pragma unroll
      for (int i = 0; i < 4; ++i)
        af[i] = *(const bf16x8*)&Ab[(wr * 64 + i * 16 + l15) * 64 + (cq ^ x7) * 8];
      #pragma unroll
      for (int j = 0; j < 4; ++j)
        bfr[j] = *(const bf16x8*)&Bb[(wc * 64 + j * 16 + l15) * 64 + (cq ^ x7) * 8];
      #pragma unroll
      for (int i = 0; i < 4; ++i)
        #pragma unroll
        for (int j = 0; j < 4; ++j)
          acc[i][j] = __builtin_amdgcn_mfma_f32_16x16x32_bf16(af[i], bfr[j], acc[i][j], 0, 0, 0);
    }
  }

  float rm_[4];
  #pragma unroll
  for (int j = 0; j < 4; ++j) rm_[j] = rsm[bn * 128 + wc * 64 + j * 16 + l15];
  #pragma unroll
  for (int i = 0; i < 4; ++i) {
    float rowsum[4];
    #pragma unroll
    for (int r = 0; r < 4; ++r) {
      const int b = bm * 128 + wr * 64 + i * 16 + quad * 4 + r;
      const float srx = SCALE * rsx[b];
      float rs = 0.f;
      #pragma unroll
      for (int j = 0; j < 4; ++j) {
        float p = __expf(acc[i][j][r] * srx * rm_[j]);
        rs += p;
        const int s = bn * 128 + wc * 64 + j * 16 + l15;
        P[(size_t)b * S_N + s] = f2bf(p);       // temporal: keep P in LLC for k_pv
      }
      rowsum[r] = rs;
    }
    #pragma unroll
    for (int r = 0; r < 4; ++r) {
      float rs = rowsum[r];
      rs += __shfl_xor(rs, 1);
      rs += __shfl_xor(rs, 2);
      rs += __shfl_xor(rs, 4);
      rs += __shfl_xor(rs, 8);
      if (l15 == 0) {
        const int b = bm * 128 + wr * 64 + i * 16 + quad * 4 + r;
        unsafeAtomicAdd(&lsum[b], rs);
      }
    }
  }
}

// ---------------- PV gemm_bt (K-split 32), DOUBLE-BUFFERED ----------------
// Opart[ks][b][d] = sum_{s in chunk} P[b][s] * Mt[d][s]
__global__ __launch_bounds__(256, 2) void k_pv(
    const unsigned short* __restrict__ P, const unsigned short* __restrict__ Mt,
    float* __restrict__ Opart) {
  __shared__ unsigned short As[2][128 * 64];
  __shared__ unsigned short Bs[2][128 * 64];
  const int t = threadIdx.x;
  const int w = t >> 6, lane = t & 63, quad = lane >> 4, l15 = lane & 15;
  const int wr = w >> 1, wc = w & 1;
  const int x7 = l15 & 7;
  const int flat = blockIdx.x;
  const int xcd = flat & 7, sl = flat >> 3;     // sl 0..127
  const int ks = xcd * 4 + (sl >> 5);           // 4 ks per XCD
  const int rem = sl & 31;
  const int bn = rem >> 3, bm = rem & 7;

  f32x4 acc[4][4];
  #pragma unroll
  for (int i = 0; i < 4; ++i)
    #pragma unroll
    for (int j = 0; j < 4; ++j) acc[i][j] = (f32x4){0.f, 0.f, 0.f, 0.f};

  const int srow = t >> 3;
  const int schunk = (t & 7) ^ (srow & 7);
  const unsigned short* gA = P  + (size_t)(bm * 128 + srow) * S_N + (size_t)ks * KCHUNK + schunk * 8;
  const unsigned short* gB = Mt + (size_t)(bn * 128 + srow) * S_N + (size_t)ks * KCHUNK + schunk * 8;
  const int lofs = w * 512;

  // preload tile 0 into buf 0
  #pragma unroll
  for (int i = 0; i < 4; ++i) {
    stage16(gA + (size_t)(i * 32) * S_N, As[0] + lofs + i * 2048);
    stage16(gB + (size_t)(i * 32) * S_N, Bs[0] + lofs + i * 2048);
  }

  for (int it = 0; it < KCHUNK / 64; ++it) {
    __syncthreads();
    if (it < KCHUNK / 64 - 1) {
      const int k0 = (it + 1) * 64;
      unsigned short* nA = As[(it + 1) & 1] + lofs;
      unsigned short* nB = Bs[(it + 1) & 1] + lofs;
      #pragma unroll
      for (int i = 0; i < 4; ++i) {
        stage16(gA + (size_t)(i * 32) * S_N + k0, nA + i * 2048);
        stage16(gB + (size_t)(i * 32) * S_N + k0, nB + i * 2048);
      }
    }
    const unsigned short* Ab = As[it & 1];
    const unsigned short* Bb = Bs[it & 1];
    #pragma unroll
    for (int kk = 0; kk < 64; kk += 32) {
      const int cq = (kk >> 3) + quad;
      bf16x8 af[4], bfr[4];
      #pragma unroll
      for (int i = 0; i < 4; ++i)
        af[i] = *(const bf16x8*)&Ab[(wr * 64 + i * 16 + l15) * 64 + (cq ^ x7) * 8];
      #pragma unroll
      for (int j = 0; j < 4; ++j)
        bfr[j] = *(const bf16x8*)&Bb[(wc * 64 + j * 16 + l15) * 64 + (cq ^ x7) * 8];
      #pragma unroll
      for (int i = 0; i < 4; ++i)
        #pragma unroll
        for (int j = 0; j < 4; ++j)
          acc[i][j] = __builtin_amdgcn_mfma_f32_16x16x32_bf16(af[i], bfr[j], acc[i][j], 0, 0, 0);
    }
  }

  float* Od = Opart + (size_t)ks * (B_N * D_N);
  #pragma unroll
  for (int i = 0; i < 4; ++i)
    #pragma unroll
    for (int r = 0; r < 4; ++r) {
      const int b = bm * 128 + wr * 64 + i * 16 + quad * 4 + r;
      #pragma unroll
      for (int j = 0; j < 4; ++j) {
        const int d = bn * 128 + wc * 64 + j * 16 + l15;
        Od[(size_t)b * D_N + d] = acc[i][j][r];
      }
    }
}

// ---------------- combine: out = (sum_ks Opart) / lsum ----------------
__global__ void k_combine(const float* __restrict__ Opart, const float* __restrict__ lsum,
                          float* __restrict__ out) {
  const int idx = blockIdx.x * 256 + threadIdx.x;  // float4 index, 131072 total
  const int b = idx >> 7;
  float4 s = {0.f, 0.f, 0.f, 0.f};
  #pragma unroll
  for (int ks = 0; ks < KSPLIT; ++ks) {
    float4 v = ((const float4*)Opart)[(size_t)ks * (B_N * D_N / 4) + idx];
    s.x += v.x; s.y += v.y; s.z += v.z; s.w += v.w;
  }
  const float inv = 1.0f / lsum[b];
  s.x *= inv; s.y *= inv; s.z *= inv; s.w *= inv;
  ((float4*)out)[idx] = s;
}

extern "C" void kernel_launch(void* const* d_in, const int* in_sizes, int n_in,
                              void* d_out, int out_size, void* d_ws, size_t ws_size,
                              hipStream_t stream) {
  const float* X = (const float*)d_in[0];
  const float* M = (const float*)d_in[1];
  char* ws = (char*)d_ws;
  unsigned short* Mbf  = (unsigned short*)(ws + OFF_MBF);
  unsigned short* Mt   = (unsigned short*)(ws + OFF_MT);
  unsigned short* Xbf  = (unsigned short*)(ws + OFF_XBF);
  unsigned short* P    = (unsigned short*)(ws + OFF_P);
  float* rsx = (float*)(ws + OFF_XNSQ);
  float* rsm = (float*)(ws + OFF_MNSQ);
  float* lsum = (float*)(ws + OFF_LSUM);
  float* Opart = (float*)(ws + OFF_OPART);    // overlays Mbf (dead after k_qk)

  (void)hipMemsetAsync(lsum, 0, B_N * sizeof(float), stream);
  k_prep_x<<<dim3(B_N), 128, 0, stream>>>(X, Xbf, rsx);
  k_prep_m<<<dim3(S_N / 64), 256, 0, stream>>>(M, Mbf, Mt, rsm);
  k_qk<<<dim3(8 * (S_N / 128)), 256, 0, stream>>>(Xbf, Mbf, rsx, rsm, P, lsum);
  k_pv<<<dim3((D_N / 128) * (B_N / 128) * KSPLIT), 256, 0, stream>>>(P, Mt, Opart);
  k_combine<<<dim3(B_N * D_N / 4 / 256), 256, 0, stream>>>(Opart, lsum, (float*)d_out);
}